// Round 1
// 445.820 us; speedup vs baseline: 1.1045x; 1.1045x over previous
//
#include <hip/hip_runtime.h>

// LSTM: B=2048, T=512, I=1, H=64, L=2, O=1. fp32 in/out.
// Round 13: i8 MFMA (16x16x64, K=64 in ONE instruction) + balanced waves.
//  - Fixed-point limb scheme: W ~ (Whi*256+Wlo)/260096, h ~ (hhi*256+hlo)/32512.
//    3 limb products per matmul (hh -> acc_hh, hl+lh -> acc_mid; drop ll):
//    one matmul = 3 MFMAs at K=64 vs 6 bf16 MFMAs at K=32. Per-CU MFMA/step
//    288 -> 144. K-byte-order of the i8 fragment cancels (A and B share the
//    same lane->k map), so only C/D layout matters (shape-determined).
//  - Balance: every wave owns ONE L1 tile + ONE L2 tile (9 MFMAs each)
//    instead of 8x12 + 8x24 -> no barrier stragglers, single code path.
//    DPP ror8 fold packs the L2 tile into lanes m>=8 (one gate4/wave),
//    exactly the r6-verified pattern (DPP unconditional, then select).
//  - k==0: L2 lanes forced h=0, c=0 (h2(-1) must be zero for the skew).
//  - Combine: P = (float)((acc_hh<<8)+acc_mid) * C_MID, exact in i32.

#define TT 512
#define HH 64
#define BT 8

typedef __attribute__((ext_vector_type(4))) int i32x4;

#define MFMAI8 __builtin_amdgcn_mfma_i32_16x16x64_i8

#define WSCALE 260096.0f   /* 32512 / 0.125 */
#define HSCALE 32512.0f    /* |h| <= 1      */
constexpr float C_MID = (float)(256.0 / (260096.0 * 32512.0));

__device__ __forceinline__ float sigm(float x) {
    return __builtin_amdgcn_rcpf(1.f + __expf(-x));
}
// NaN-safe tanh: 1 - 2/(1+e^{2x})
__device__ __forceinline__ float tanh_f(float x) {
    return 1.f - 2.f * __builtin_amdgcn_rcpf(1.f + __expf(2.f * x));
}
__device__ __forceinline__ float gate4(float pi, float pf, float pg, float po, float& c) {
    float gi = sigm(pi), gf = sigm(pf), gg = tanh_f(pg), go = sigm(po);
    c = fmaf(gf, c, gi * gg);
    return go * tanh_f(c);
}
// lane i <- lane (i^8) within each row of 16 (row_ror:8, HW-verified r6).
// MUST be called with all 64 lanes active.
__device__ __forceinline__ float dpp_ror8(float v) {
    return __int_as_float(__builtin_amdgcn_update_dpp(
        0, __float_as_int(v), 0x128, 0xF, 0xF, true));
}
// 16 consecutive fp32 weights -> i8 hi/lo limb fragments (4 bytes/reg).
__device__ __forceinline__ void cvtW16(const float* __restrict__ p, i32x4& hi, i32x4& lo) {
    #pragma unroll
    for (int r = 0; r < 4; ++r) {
        int hw = 0, lw = 0;
        #pragma unroll
        for (int b = 0; b < 4; ++b) {
            int wq = (int)rintf(p[r * 4 + b] * WSCALE);   // |wq| <= 32512
            int h8 = (wq + 128) >> 8;                     // [-127,127]
            int l8 = wq - (h8 << 8);                      // [-128,127]
            hw |= (h8 & 0xFF) << (8 * b);
            lw |= (l8 & 0xFF) << (8 * b);
        }
        hi[r] = hw; lo[r] = lw;
    }
}

__global__ __launch_bounds__(1024) void lstm_mfma(
    const float* __restrict__ x,
    const float* __restrict__ Wih0, const float* __restrict__ Whh0,
    const float* __restrict__ bih0, const float* __restrict__ bhh0,
    const float* __restrict__ Wih1, const float* __restrict__ Whh1,
    const float* __restrict__ bih1, const float* __restrict__ bhh1,
    const float* __restrict__ fcW, const float* __restrict__ fcb,
    float* __restrict__ out)
{
    __shared__ float xs[BT][TT + 1];                        // 16.4 KB
    // h limbs in i8 B-layout: [layer][buf][limb][row][byte];
    // B[k][n]: row = (k>>4)*16 + n, byte = k&15. Batches n>=8 stay 0.
    __shared__ __align__(16) signed char aH[2][2][2][64][16];  // 8 KB
    __shared__ float hF[BT][HH + 1];
    __shared__ float fcw_s[HH];

    const int t    = threadIdx.x;
    const int lane = t & 63;
    const int w    = t >> 6;          // wave 0..15 == M-tile index
    const int b0   = blockIdx.x * BT;
    const int m    = lane & 15;       // A-row-within-tile AND D-col
    const int q    = lane >> 4;       // quad
    const int ts   = m >> 3;          // 0: this lane finalizes L1, 1: L2
    const int bpk  = m & 7;           // this lane's batch
    const int jpk  = 4 * w + q;       // this lane's hidden unit

    // ---- stage x; zero h limb buffers ----
    for (int i = t; i < BT * TT; i += 1024)
        xs[i >> 9][i & (TT - 1)] = x[(size_t)(b0 + (i >> 9)) * TT + (i & (TT - 1))];
    {
        int* z = (int*)aH;
        for (int i = t; i < 2048; i += 1024) z[i] = 0;
    }
    if (t < HH) fcw_s[t] = fcW[t];

    // ---- persistent A-frag weights (i8 limbs): tile w of all 3 matrices ----
    // A-row m in tile w -> gate-row rho = (m&3)*64 + 4*w + (m>>2);
    // k = q*16 + byte (contiguous 16 floats of the row).
    i32x4 A0h, A0l, I1h, I1l, H1h, H1l;
    {
        const int rho = (m & 3) * 64 + 4 * w + (m >> 2);
        cvtW16(Whh0 + rho * HH + q * 16, A0h, A0l);
        cvtW16(Wih1 + rho * HH + q * 16, I1h, I1l);
        cvtW16(Whh1 + rho * HH + q * 16, H1h, H1l);
    }

    // ---- per-lane combine constants ----
    float wxb[4], bia[4];
    #pragma unroll
    for (int v = 0; v < 4; ++v) {
        const int r = v * 64 + jpk;
        if (ts) { wxb[v] = 0.f;     bia[v] = bih1[r] + bhh1[r]; }
        else    { wxb[v] = Wih0[r]; bia[v] = bih0[r] + bhh0[r]; }
    }
    // scatter target for this lane's h limb bytes
    const int wl = ((jpk >> 4) << 4) + bpk;   // row
    const int wb = jpk & 15;                  // byte
    float c = 0.f;

    __syncthreads();

    #pragma unroll 2
    for (int k = 0; k < TT; ++k) {
        const int p = k & 1, pn = p ^ 1;
        i32x4 bh1 = *(const i32x4*)&aH[0][p][0][lane][0];
        i32x4 bl1 = *(const i32x4*)&aH[0][p][1][lane][0];
        i32x4 bh2 = *(const i32x4*)&aH[1][p][0][lane][0];
        i32x4 bl2 = *(const i32x4*)&aH[1][p][1][lane][0];
        i32x4 z4 = {0, 0, 0, 0};
        i32x4 aHHr = z4, aMDr = z4, bHHr = z4, bMDr = z4;
        // L1 tile: Whh0 * h1(k-1)
        aHHr = MFMAI8(A0h, bh1, aHHr, 0, 0, 0);
        bHHr = MFMAI8(I1h, bh1, bHHr, 0, 0, 0);
        aMDr = MFMAI8(A0h, bl1, aMDr, 0, 0, 0);
        bMDr = MFMAI8(I1h, bl1, bMDr, 0, 0, 0);
        aMDr = MFMAI8(A0l, bh1, aMDr, 0, 0, 0);
        bMDr = MFMAI8(I1l, bh1, bMDr, 0, 0, 0);
        // L2 tile: + Whh1 * h2(k-2)
        bHHr = MFMAI8(H1h, bh2, bHHr, 0, 0, 0);
        bMDr = MFMAI8(H1h, bl2, bMDr, 0, 0, 0);
        bMDr = MFMAI8(H1l, bh2, bMDr, 0, 0, 0);

        float pk4[4];
        #pragma unroll
        for (int r = 0; r < 4; ++r) {
            float pa = (float)((aHHr[r] << 8) + aMDr[r]) * C_MID;
            float pb = (float)((bHHr[r] << 8) + bMDr[r]) * C_MID;
            float mv = dpp_ror8(pb);      // unconditional, all lanes active
            pk4[r] = (m < 8) ? pa : mv;
        }
        float xb = xs[bpk][k];
        float hv = gate4(pk4[0] + fmaf(wxb[0], xb, bia[0]),
                         pk4[1] + fmaf(wxb[1], xb, bia[1]),
                         pk4[2] + fmaf(wxb[2], xb, bia[2]),
                         pk4[3] + fmaf(wxb[3], xb, bia[3]), c);
        if (k == 0) {                     // h2(-1) must be exactly 0
            hv = ts ? 0.f : hv;
            c  = ts ? 0.f : c;
        }
        // h -> 16-bit fixed point -> two i8 limbs (round-to-nearest-even)
        int hq = __float_as_int(fmaf(hv, HSCALE, 12582912.f)) - 0x4B400000;
        int h8 = (hq + 128) >> 8;
        int l8 = hq - (h8 << 8);
        aH[ts][pn][0][wl][wb] = (signed char)h8;
        aH[ts][pn][1][wl][wb] = (signed char)l8;
        __syncthreads();
    }

    // ---- epilogue: h2(TT-1) from h1(TT-1) and h2(TT-2) (both in buf 0) ----
    {
        i32x4 bh1 = *(const i32x4*)&aH[0][0][0][lane][0];
        i32x4 bl1 = *(const i32x4*)&aH[0][0][1][lane][0];
        i32x4 bh2 = *(const i32x4*)&aH[1][0][0][lane][0];
        i32x4 bl2 = *(const i32x4*)&aH[1][0][1][lane][0];
        i32x4 z4 = {0, 0, 0, 0};
        i32x4 bHHr = z4, bMDr = z4;
        bHHr = MFMAI8(I1h, bh1, bHHr, 0, 0, 0);
        bMDr = MFMAI8(I1h, bl1, bMDr, 0, 0, 0);
        bMDr = MFMAI8(I1l, bh1, bMDr, 0, 0, 0);
        bHHr = MFMAI8(H1h, bh2, bHHr, 0, 0, 0);
        bMDr = MFMAI8(H1h, bl2, bMDr, 0, 0, 0);
        bMDr = MFMAI8(H1l, bh2, bMDr, 0, 0, 0);
        float pk4[4];
        #pragma unroll
        for (int r = 0; r < 4; ++r) {
            float pb = (float)((bHHr[r] << 8) + bMDr[r]) * C_MID;
            pk4[r] = dpp_ror8(pb);
        }
        float hv = gate4(pk4[0] + bia[0], pk4[1] + bia[1],
                         pk4[2] + bia[2], pk4[3] + bia[3], c);
        if (ts) hF[bpk][jpk] = hv;
    }
    __syncthreads();

    // ---- final FC: out[b] = fcW . h2(TT-1)[b] + fcb ----
    if (t < BT) {
        float s = fcb[0];
        #pragma unroll 8
        for (int j = 0; j < HH; ++j)
            s = fmaf(hF[t][j], fcw_s[j], s);
        out[b0 + t] = s;
    }
}

extern "C" void kernel_launch(void* const* d_in, const int* in_sizes, int n_in,
                              void* d_out, int out_size, void* d_ws, size_t ws_size,
                              hipStream_t stream) {
    const float* x    = (const float*)d_in[0];
    const float* Wih0 = (const float*)d_in[1];
    const float* Whh0 = (const float*)d_in[2];
    const float* bih0 = (const float*)d_in[3];
    const float* bhh0 = (const float*)d_in[4];
    const float* Wih1 = (const float*)d_in[5];
    const float* Whh1 = (const float*)d_in[6];
    const float* bih1 = (const float*)d_in[7];
    const float* bhh1 = (const float*)d_in[8];
    const float* fcW  = (const float*)d_in[9];
    const float* fcb  = (const float*)d_in[10];
    float* out = (float*)d_out;

    lstm_mfma<<<dim3(2048 / BT), dim3(1024), 0, stream>>>(
        x, Wih0, Whh0, bih0, bhh0, Wih1, Whh1, bih1, bhh1, fcW, fcb, out);
}

// Round 2
// 433.881 us; speedup vs baseline: 1.1349x; 1.0275x over previous
//
#include <hip/hip_runtime.h>

// LSTM: B=2048, T=512, I=1, H=64, L=2, O=1. fp32 in/out.
// Round 14: VALU-cut on the r13 i8-MFMA structure (9 MFMA/wave unchanged).
//  - exp2-domain gates: combine-const/wxb/bia pre-scaled by log2e (2log2e for
//    the g gate) -> sigm = rcp(1+exp2(-p)) (3 ops), tanh_g = 4 ops.
//  - Integer DPP-fold: junk cols are exactly 0 in every accumulator, so
//    pk = a_acc + dpp_ror8(b_acc) (int add) replaces float dual-path+cndmask.
//  - Offset-binary lo limb: store hi=hq>>8, lo=(hq&255)-128 (= hq^0x80).
//    The +128*sum(Whi) compensation lives in the accumulator INIT registers,
//    computed once at setup with a ones-vector MFMA. Lo-planes init to 0x80
//    (encoded zero); junk cols then cancel exactly (corr - 128*sum = 0).
//  - sigma byte-permute of K-slots (A/B k-order cancels): writer byte
//    sigma(j)=((j&3)<<2)|(j>>2) -> wave's 64 byte-stores hit 32 banks 2-way
//    (was 4-way same-dword merge, 8.4M conflict cycles/dispatch).

#define TT 512
#define HH 64
#define BT 8

typedef __attribute__((ext_vector_type(4))) int i32x4;

#define MFMAI8 __builtin_amdgcn_mfma_i32_16x16x64_i8

#define WSCALE 260096.0f   /* 32512 / 0.125 */
#define HSCALE 32512.0f    /* |h| <= 1      */
#define LOG2E  1.44269504f
// combine constants: P_int * C -> pre-activation already in exp2 domain
constexpr float C_SIG = (float)(256.0 / (260096.0 * 32512.0) * 1.4426950408889634);
constexpr float C_TGH = (float)(2.0 * 256.0 / (260096.0 * 32512.0) * 1.4426950408889634);

// 1-instruction exp2 (v_exp_f32 IS exp2); neg variant keeps the free modifier.
__device__ __forceinline__ float exp2_hw(float x) {
    float r; asm("v_exp_f32 %0, %1" : "=v"(r) : "v"(x)); return r;
}
__device__ __forceinline__ float exp2n_hw(float x) {
    float r; asm("v_exp_f32 %0, -%1" : "=v"(r) : "v"(x)); return r;
}
// inputs pre-scaled: p0,p1,p3 by log2e; p2 by 2*log2e. c stays in real units.
__device__ __forceinline__ float gate4s(float p0, float p1, float p2, float p3, float& c) {
    float gi = __builtin_amdgcn_rcpf(1.f + exp2n_hw(p0));
    float gf = __builtin_amdgcn_rcpf(1.f + exp2n_hw(p1));
    float gg = 1.f - 2.f * __builtin_amdgcn_rcpf(1.f + exp2_hw(p2));
    float go = __builtin_amdgcn_rcpf(1.f + exp2n_hw(p3));
    c = fmaf(gf, c, gi * gg);
    float tc = 1.f - 2.f * __builtin_amdgcn_rcpf(1.f + exp2_hw(c * (2.f * LOG2E)));
    return go * tc;
}
// lane i <- lane (i^8) within each row of 16 (row_ror:8, HW-verified r6).
// All 64 lanes active at every call site (enclosing branches wave-uniform).
__device__ __forceinline__ int dpp_ror8_i(int v) {
    return __builtin_amdgcn_update_dpp(v, v, 0x128, 0xF, 0xF, true);
}
// 16 fp32 weights of one row-quarter -> i8 hi/lo limb frags, sigma-permuted:
// byte b of reg r holds W[base + 4*b + r]  (sigma(r*4+b) = 4b+r, involution).
__device__ __forceinline__ void cvtW16(const float* __restrict__ p, i32x4& hi, i32x4& lo) {
    #pragma unroll
    for (int r = 0; r < 4; ++r) {
        int hw = 0, lw = 0;
        #pragma unroll
        for (int b = 0; b < 4; ++b) {
            int wq = (int)rintf(p[4 * b + r] * WSCALE);   // |wq| <= 32512
            int h8 = (wq + 128) >> 8;                     // [-127,127]
            int l8 = wq - (h8 << 8);                      // [-128,127]
            hw |= (h8 & 0xFF) << (8 * b);
            lw |= (l8 & 0xFF) << (8 * b);
        }
        hi[r] = hw; lo[r] = lw;
    }
}

__global__ __launch_bounds__(1024) void lstm_mfma(
    const float* __restrict__ x,
    const float* __restrict__ Wih0, const float* __restrict__ Whh0,
    const float* __restrict__ bih0, const float* __restrict__ bhh0,
    const float* __restrict__ Wih1, const float* __restrict__ Whh1,
    const float* __restrict__ bih1, const float* __restrict__ bhh1,
    const float* __restrict__ fcW, const float* __restrict__ fcb,
    float* __restrict__ out)
{
    __shared__ float xs[BT][TT + 1];                        // 16.4 KB
    // h limbs in i8 B-layout: [layer][buf][limb][row][byte];
    // byte j of row holds unit u = (row>>4)*16 + sigma(j). Lo-plane stores
    // (hq&255)-128; encoded zero = 0x80. Junk rows (n>=8) keep init forever.
    __shared__ __align__(16) signed char aH[2][2][2][64][16];  // 8 KB
    __shared__ float hF[BT][HH + 1];
    __shared__ float fcw_s[HH];

    const int t    = threadIdx.x;
    const int lane = t & 63;
    const int w    = t >> 6;          // wave 0..15 == M-tile index
    const int b0   = blockIdx.x * BT;
    const int m    = lane & 15;       // A-row-within-tile AND D-col
    const int q    = lane >> 4;       // quad
    const int ts   = m >> 3;          // 0: this lane finalizes L1, 1: L2
    const int bpk  = m & 7;           // this lane's batch
    const int jpk  = 4 * w + q;       // this lane's hidden unit

    // ---- stage x; init limb planes (hi=0, lo=0x80 = encoded zero) ----
    for (int i = t; i < BT * TT; i += 1024)
        xs[i >> 9][i & (TT - 1)] = x[(size_t)(b0 + (i >> 9)) * TT + (i & (TT - 1))];
    {
        int* z = (int*)aH;
        for (int i = t; i < 2048; i += 1024)
            z[i] = ((i >> 8) & 1) ? 0x80808080 : 0;   // 256 ints per limb plane
    }
    if (t < HH) fcw_s[t] = fcW[t];

    // ---- persistent A-frag weights (i8 limbs): tile w of all 3 matrices ----
    // A-row m in tile w -> gate-row rho = (m&3)*64 + 4*w + (m>>2)
    i32x4 A0h, A0l, I1h, I1l, H1h, H1l;
    {
        const int rho = (m & 3) * 64 + 4 * w + (m >> 2);
        cvtW16(Whh0 + rho * HH + q * 16, A0h, A0l);
        cvtW16(Wih1 + rho * HH + q * 16, I1h, I1l);
        cvtW16(Whh1 + rho * HH + q * 16, H1h, H1l);
    }

    // ---- accumulator-init correction: +128*sum(Whi_row) per (r, col) ----
    // One-time ones-vector MFMAs; D follows the shape's C/D layout, so each
    // position gets exactly its own row-sum.
    i32x4 corrA, corrB;
    {
        i32x4 ones; ones[0] = 0x01010101; ones[1] = 0x01010101;
        ones[2] = 0x01010101; ones[3] = 0x01010101;
        i32x4 zz = {0, 0, 0, 0};
        i32x4 Sa = MFMAI8(A0h, ones, zz, 0, 0, 0);
        i32x4 Sb = MFMAI8(I1h, ones, zz, 0, 0, 0);
        Sb = MFMAI8(H1h, ones, Sb, 0, 0, 0);
        #pragma unroll
        for (int r = 0; r < 4; ++r) { corrA[r] = Sa[r] << 7; corrB[r] = Sb[r] << 7; }
    }

    // ---- per-lane combine constants (pre-scaled into exp2 domain) ----
    float wxb[4], bia[4];
    #pragma unroll
    for (int v = 0; v < 4; ++v) {
        const int r = v * 64 + jpk;
        const float sc = (v == 2) ? 2.f * LOG2E : LOG2E;
        if (ts) { wxb[v] = 0.f;          bia[v] = (bih1[r] + bhh1[r]) * sc; }
        else    { wxb[v] = Wih0[r] * sc; bia[v] = (bih0[r] + bhh0[r]) * sc; }
    }
    // scatter target: row wl, byte wb = sigma(jpk&15) -> 32 banks, 2-way
    const int wl = ((jpk >> 4) << 4) + bpk;
    const int wb = ((jpk & 3) << 2) | ((jpk >> 2) & 3);
    float c = 0.f;

    __syncthreads();

    #pragma unroll 2
    for (int k = 0; k < TT; ++k) {
        const int p = k & 1, pn = p ^ 1;
        i32x4 bh1 = *(const i32x4*)&aH[0][p][0][lane][0];
        i32x4 bl1 = *(const i32x4*)&aH[0][p][1][lane][0];
        i32x4 bh2 = *(const i32x4*)&aH[1][p][0][lane][0];
        i32x4 bl2 = *(const i32x4*)&aH[1][p][1][lane][0];
        i32x4 z4 = {0, 0, 0, 0};
        i32x4 aHHr = z4, bHHr = z4;
        i32x4 aMDr = corrA, bMDr = corrB;
        // L1 tile: Whh0 * h1(k-1)
        aHHr = MFMAI8(A0h, bh1, aHHr, 0, 0, 0);
        bHHr = MFMAI8(I1h, bh1, bHHr, 0, 0, 0);
        aMDr = MFMAI8(A0h, bl1, aMDr, 0, 0, 0);
        bMDr = MFMAI8(I1h, bl1, bMDr, 0, 0, 0);
        aMDr = MFMAI8(A0l, bh1, aMDr, 0, 0, 0);
        bMDr = MFMAI8(I1l, bh1, bMDr, 0, 0, 0);
        // L2 tile: + Whh1 * h2(k-2)
        bHHr = MFMAI8(H1h, bh2, bHHr, 0, 0, 0);
        bMDr = MFMAI8(H1h, bl2, bMDr, 0, 0, 0);
        bMDr = MFMAI8(H1l, bh2, bMDr, 0, 0, 0);

        float xb = xs[bpk][k];
        float pre[4];
        #pragma unroll
        for (int r = 0; r < 4; ++r) {
            // junk cols are exactly 0 on both sides -> pure additive fold
            int hh = aHHr[r] + dpp_ror8_i(bHHr[r]);
            int md = aMDr[r] + dpp_ror8_i(bMDr[r]);
            float P = (float)((hh << 8) + md);
            const float Cr = (r == 2) ? C_TGH : C_SIG;
            pre[r] = fmaf(P, Cr, fmaf(wxb[r], xb, bia[r]));
        }
        float hv = gate4s(pre[0], pre[1], pre[2], pre[3], c);
        if (k == 0) {                     // h2(-1) must be exactly 0
            hv = ts ? 0.f : hv;
            c  = ts ? 0.f : c;
        }
        // h -> 16-bit fixed point (RNE); exact split: hi=hq>>8, lo byte=hq^0x80
        int hq = __float_as_int(fmaf(hv, HSCALE, 12582912.f)) - 0x4B400000;
        aH[ts][pn][0][wl][wb] = (signed char)(hq >> 8);
        aH[ts][pn][1][wl][wb] = (signed char)(hq ^ 0x80);
        __syncthreads();
    }

    // ---- epilogue: h2(TT-1) from h1(TT-1) and h2(TT-2) (both in buf 0) ----
    {
        i32x4 bh1 = *(const i32x4*)&aH[0][0][0][lane][0];
        i32x4 bl1 = *(const i32x4*)&aH[0][0][1][lane][0];
        i32x4 bh2 = *(const i32x4*)&aH[1][0][0][lane][0];
        i32x4 bl2 = *(const i32x4*)&aH[1][0][1][lane][0];
        i32x4 z4 = {0, 0, 0, 0};
        i32x4 bHHr = z4, bMDr = corrB;
        bHHr = MFMAI8(I1h, bh1, bHHr, 0, 0, 0);
        bMDr = MFMAI8(I1h, bl1, bMDr, 0, 0, 0);
        bMDr = MFMAI8(I1l, bh1, bMDr, 0, 0, 0);
        bHHr = MFMAI8(H1h, bh2, bHHr, 0, 0, 0);
        bMDr = MFMAI8(H1h, bl2, bMDr, 0, 0, 0);
        bMDr = MFMAI8(H1l, bh2, bMDr, 0, 0, 0);
        float pre[4];
        #pragma unroll
        for (int r = 0; r < 4; ++r) {
            int hh = dpp_ror8_i(bHHr[r]);
            int md = dpp_ror8_i(bMDr[r]);
            float P = (float)((hh << 8) + md);
            const float Cr = (r == 2) ? C_TGH : C_SIG;
            pre[r] = fmaf(P, Cr, bia[r]);
        }
        float hv = gate4s(pre[0], pre[1], pre[2], pre[3], c);
        if (ts) hF[bpk][jpk] = hv;
    }
    __syncthreads();

    // ---- final FC: out[b] = fcW . h2(TT-1)[b] + fcb ----
    if (t < BT) {
        float s = fcb[0];
        #pragma unroll 8
        for (int j = 0; j < HH; ++j)
            s = fmaf(hF[t][j], fcw_s[j], s);
        out[b0 + t] = s;
    }
}

extern "C" void kernel_launch(void* const* d_in, const int* in_sizes, int n_in,
                              void* d_out, int out_size, void* d_ws, size_t ws_size,
                              hipStream_t stream) {
    const float* x    = (const float*)d_in[0];
    const float* Wih0 = (const float*)d_in[1];
    const float* Whh0 = (const float*)d_in[2];
    const float* bih0 = (const float*)d_in[3];
    const float* bhh0 = (const float*)d_in[4];
    const float* Wih1 = (const float*)d_in[5];
    const float* Whh1 = (const float*)d_in[6];
    const float* bih1 = (const float*)d_in[7];
    const float* bhh1 = (const float*)d_in[8];
    const float* fcW  = (const float*)d_in[9];
    const float* fcb  = (const float*)d_in[10];
    float* out = (float*)d_out;

    lstm_mfma<<<dim3(2048 / BT), dim3(1024), 0, stream>>>(
        x, Wih0, Whh0, bih0, bhh0, Wih1, Whh1, bih1, bhh1, fcW, fcb, out);
}